// Round 1
// baseline (7904.391 us; speedup 1.0000x reference)
//
#include <hip/hip_runtime.h>
#include <math.h>

#define BS 256
static constexpr int NN = 100000;   // nodes
static constexpr int EE = 1600000;  // directed edges (excl. self loops)

static inline int cdiv(long long a, int b) { return (int)((a + b - 1) / b); }

// ---------------- activation ----------------
template <int ACT>
__device__ __forceinline__ float act_f(float v) {
    if (ACT == 1) return fmaxf(v, 0.0f);
    if (ACT == 2) return tanhf(v);
    return v;
}

// ---------------- degree / norm prep ----------------
__global__ void k_deg_init(float* __restrict__ deg) {
    int i = blockIdx.x * BS + threadIdx.x;
    if (i < NN) deg[i] = 1.0f;  // self-loop
}

__global__ void k_deg_acc(const int* __restrict__ dst, float* __restrict__ deg) {
    int e = blockIdx.x * BS + threadIdx.x;
    if (e < EE) atomicAdd(&deg[dst[e]], 1.0f);
}

__global__ void k_dis(const float* __restrict__ deg, float* __restrict__ dis,
                      float* __restrict__ selfn) {
    int i = blockIdx.x * BS + threadIdx.x;
    if (i < NN) {
        float d = deg[i];
        dis[i] = rsqrtf(d);
        selfn[i] = 1.0f / d;
    }
}

__global__ void k_norm(const int* __restrict__ src, const int* __restrict__ dst,
                       const float* __restrict__ dis, float* __restrict__ norm) {
    int e = blockIdx.x * BS + threadIdx.x;
    if (e < EE) norm[e] = dis[src[e]] * dis[dst[e]];
}

// ---------------- agg init: agg[n,c] = v[n,c] * selfnorm[n] ----------------
template <int C>
__global__ void k_init(const float* __restrict__ v, const float* __restrict__ selfn,
                       float* __restrict__ agg) {
    int i = blockIdx.x * BS + threadIdx.x;
    if (i < NN * C) agg[i] = v[i] * selfn[i / C];
}

// ---------------- scatter: agg[dst,:] += h[src,:] * norm[e] ----------------
// one thread per (edge, 4-channel group); consecutive threads cover one edge's
// contiguous row -> coalesced gather + contiguous atomic addresses
template <int C>
__global__ void k_scatter(const float* __restrict__ h, const int* __restrict__ src,
                          const int* __restrict__ dst, const float* __restrict__ norm,
                          float* __restrict__ agg) {
    static_assert(C % 4 == 0, "C%4");
    constexpr int V = C / 4;
    int t = blockIdx.x * BS + threadIdx.x;
    int e = t / V;
    int v = t % V;
    if (e >= EE) return;
    int s = src[e], d = dst[e];
    float w = norm[e];
    float4 hv = ((const float4*)(h + (size_t)s * C))[v];
    float* ap = agg + (size_t)d * C + v * 4;
    atomicAdd(ap + 0, hv.x * w);
    atomicAdd(ap + 1, hv.y * w);
    atomicAdd(ap + 2, hv.z * w);
    atomicAdd(ap + 3, hv.w * w);
}

__global__ void k_scatter3(const float* __restrict__ h, const int* __restrict__ src,
                           const int* __restrict__ dst, const float* __restrict__ norm,
                           float* __restrict__ agg) {
    int e = blockIdx.x * BS + threadIdx.x;
    if (e >= EE) return;
    int s = src[e], d = dst[e];
    float w = norm[e];
    const float* hp = h + (size_t)s * 3;
    float* ap = agg + (size_t)d * 3;
    atomicAdd(ap + 0, hp[0] * w);
    atomicAdd(ap + 1, hp[1] * w);
    atomicAdd(ap + 2, hp[2] * w);
}

// ---------------- finalize: out = act(agg + b) ----------------
template <int C, int ACT>
__global__ void k_fin(const float* __restrict__ agg, const float* __restrict__ b,
                      float* __restrict__ out) {
    int i = blockIdx.x * BS + threadIdx.x;
    if (i < NN * C) out[i] = act_f<ACT>(agg[i] + b[i % C]);
}

// ---------------- simple matmul (small CIN): thread per output elem ----------------
template <int CIN, int COUT, int ACT, bool HASB, bool AGG>
__global__ void k_mm_simple(const float* __restrict__ x, const float* __restrict__ w,
                            const float* __restrict__ b, float* __restrict__ out,
                            const float* __restrict__ selfn, float* __restrict__ aggout) {
    int i = blockIdx.x * BS + threadIdx.x;
    if (i >= NN * COUT) return;
    int n = i / COUT, c = i % COUT;
    const float* xr = x + (size_t)n * CIN;
    float acc = HASB ? b[c] : 0.0f;
#pragma unroll
    for (int ci = 0; ci < CIN; ++ci) acc = fmaf(xr[ci], w[ci * COUT + c], acc);
    float v = act_f<ACT>(acc);
    out[i] = v;
    if (AGG) aggout[i] = v * selfn[n];
}

// ---------------- vectorized matmul: thread computes TM=8 rows for one col ----------------
template <int CIN, int COUT, int ACT, bool HASB, bool AGG>
__global__ void k_mm_vec(const float* __restrict__ x, const float* __restrict__ w,
                         const float* __restrict__ b, float* __restrict__ out,
                         const float* __restrict__ selfn, float* __restrict__ aggout) {
    static_assert(CIN % 4 == 0, "CIN%4");
    constexpr int TM = 8;
    constexpr int CIN4 = CIN / 4;
    constexpr int RG = NN / TM;  // 12500
    int i = blockIdx.x * BS + threadIdx.x;
    if (i >= RG * COUT) return;
    int c = i % COUT;
    int n0 = (i / COUT) * TM;
    float acc[TM];
    float bb = HASB ? b[c] : 0.0f;
#pragma unroll
    for (int r = 0; r < TM; ++r) acc[r] = bb;
    const float4* x4 = (const float4*)x;
    for (int k = 0; k < CIN4; ++k) {
        float w0 = w[(4 * k + 0) * COUT + c];
        float w1 = w[(4 * k + 1) * COUT + c];
        float w2 = w[(4 * k + 2) * COUT + c];
        float w3 = w[(4 * k + 3) * COUT + c];
#pragma unroll
        for (int r = 0; r < TM; ++r) {
            float4 xv = x4[(size_t)(n0 + r) * CIN4 + k];
            acc[r] = fmaf(xv.x, w0, fmaf(xv.y, w1, fmaf(xv.z, w2, fmaf(xv.w, w3, acc[r]))));
        }
    }
#pragma unroll
    for (int r = 0; r < TM; ++r) {
        float v = act_f<ACT>(acc[r]);
        size_t o = (size_t)(n0 + r) * COUT + c;
        out[o] = v;
        if (AGG) aggout[o] = v * selfn[n0 + r];
    }
}

extern "C" void kernel_launch(void* const* d_in, const int* in_sizes, int n_in,
                              void* d_out, int out_size, void* d_ws, size_t ws_size,
                              hipStream_t stream) {
    const float* x = (const float*)d_in[0];
    const int* ei = (const int*)d_in[1];
    const int* src = ei;
    const int* dst = ei + EE;
    const float* eg1_w = (const float*)d_in[2];  const float* eg1_b = (const float*)d_in[3];
    const float* eg2_w = (const float*)d_in[4];  const float* eg2_b = (const float*)d_in[5];
    const float* eg3_w = (const float*)d_in[6];  const float* eg3_b = (const float*)d_in[7];
    const float* eg4_w = (const float*)d_in[8];  const float* eg4_b = (const float*)d_in[9];
    const float* el1_w = (const float*)d_in[10]; const float* el1_b = (const float*)d_in[11];
    const float* el2_w = (const float*)d_in[12]; const float* el2_b = (const float*)d_in[13];
    const float* dl1_w = (const float*)d_in[14]; const float* dl1_b = (const float*)d_in[15];
    const float* dl2_w = (const float*)d_in[16]; const float* dl2_b = (const float*)d_in[17];
    const float* dg1_w = (const float*)d_in[18]; const float* dg1_b = (const float*)d_in[19];
    const float* dg2_w = (const float*)d_in[20]; const float* dg2_b = (const float*)d_in[21];
    const float* dg3_w = (const float*)d_in[22]; const float* dg3_b = (const float*)d_in[23];
    const float* dg4_w = (const float*)d_in[24]; const float* dg4_b = (const float*)d_in[25];
    float* out = (float*)d_out;

    // workspace layout (floats): deg N | dis N | selfn N | norm E | bufA 160N | bufB 160N | bufC 80N
    float* ws = (float*)d_ws;
    float* deg = ws;
    float* dis = deg + NN;
    float* selfn = dis + NN;
    float* norm = selfn + NN;
    float* bufA = norm + EE;
    float* bufB = bufA + (size_t)160 * NN;
    float* bufC = bufB + (size_t)160 * NN;

    // ---- degree / norm prep ----
    k_deg_init<<<cdiv(NN, BS), BS, 0, stream>>>(deg);
    k_deg_acc<<<cdiv(EE, BS), BS, 0, stream>>>(dst, deg);
    k_dis<<<cdiv(NN, BS), BS, 0, stream>>>(deg, dis, selfn);
    k_norm<<<cdiv(EE, BS), BS, 0, stream>>>(src, dst, dis, norm);

    // ---- eg1 (3->160), AGG-first (aggregate 3 channels, then matmul) ----
    k_init<3><<<cdiv(3LL * NN, BS), BS, 0, stream>>>(x, selfn, bufC);
    k_scatter3<<<cdiv(EE, BS), BS, 0, stream>>>(x, src, dst, norm, bufC);
    k_mm_simple<3, 160, 1, true, false><<<cdiv(160LL * NN, BS), BS, 0, stream>>>(
        bufC, eg1_w, eg1_b, bufA, nullptr, nullptr);

    // ---- eg2 (160->80), MM-first: h=bufB, agg-init fused into epilogue ----
    k_mm_vec<160, 80, 0, false, true><<<cdiv((NN / 8) * 80LL, BS), BS, 0, stream>>>(
        bufA, eg2_w, nullptr, bufB, selfn, bufC);
    k_scatter<80><<<cdiv(EE * 20LL, BS), BS, 0, stream>>>(bufB, src, dst, norm, bufC);
    k_fin<80, 1><<<cdiv(80LL * NN, BS), BS, 0, stream>>>(bufC, eg2_b, bufA);

    // ---- eg3 (80->40), MM-first ----
    k_mm_vec<80, 40, 0, false, true><<<cdiv((NN / 8) * 40LL, BS), BS, 0, stream>>>(
        bufA, eg3_w, nullptr, bufB, selfn, bufC);
    k_scatter<40><<<cdiv(EE * 10LL, BS), BS, 0, stream>>>(bufB, src, dst, norm, bufC);
    k_fin<40, 1><<<cdiv(40LL * NN, BS), BS, 0, stream>>>(bufC, eg3_b, bufA);

    // ---- eg4 (40->20), MM-first ----
    k_mm_vec<40, 20, 0, false, true><<<cdiv((NN / 8) * 20LL, BS), BS, 0, stream>>>(
        bufA, eg4_w, nullptr, bufB, selfn, bufC);
    k_scatter<20><<<cdiv(EE * 5LL, BS), BS, 0, stream>>>(bufB, src, dst, norm, bufC);
    k_fin<20, 1><<<cdiv(20LL * NN, BS), BS, 0, stream>>>(bufC, eg4_b, bufA);

    // ---- dense latent stack ----
    k_mm_vec<20, 10, 1, true, false><<<cdiv((NN / 8) * 10LL, BS), BS, 0, stream>>>(
        bufA, el1_w, el1_b, bufB, nullptr, nullptr);
    k_mm_simple<10, 3, 0, true, false><<<cdiv(3LL * NN, BS), BS, 0, stream>>>(
        bufB, el2_w, el2_b, bufA, nullptr, nullptr);
    k_mm_simple<3, 10, 1, true, false><<<cdiv(10LL * NN, BS), BS, 0, stream>>>(
        bufA, dl1_w, dl1_b, bufB, nullptr, nullptr);
    // dl2 also produces dg1's agg-init (bufC, 20ch) in its epilogue
    k_mm_simple<10, 20, 1, true, true><<<cdiv(20LL * NN, BS), BS, 0, stream>>>(
        bufB, dl2_w, dl2_b, bufA, selfn, bufC);

    // ---- dg1 (20->40), AGG-first (agg-init already in bufC) ----
    k_scatter<20><<<cdiv(EE * 5LL, BS), BS, 0, stream>>>(bufA, src, dst, norm, bufC);
    k_mm_vec<20, 40, 1, true, false><<<cdiv((NN / 8) * 40LL, BS), BS, 0, stream>>>(
        bufC, dg1_w, dg1_b, bufB, nullptr, nullptr);

    // ---- dg2 (40->80), AGG-first ----
    k_init<40><<<cdiv(40LL * NN, BS), BS, 0, stream>>>(bufB, selfn, bufC);
    k_scatter<40><<<cdiv(EE * 10LL, BS), BS, 0, stream>>>(bufB, src, dst, norm, bufC);
    k_mm_vec<40, 80, 1, true, false><<<cdiv((NN / 8) * 80LL, BS), BS, 0, stream>>>(
        bufC, dg2_w, dg2_b, bufA, nullptr, nullptr);

    // ---- dg3 (80->160), AGG-first ----
    k_init<80><<<cdiv(80LL * NN, BS), BS, 0, stream>>>(bufA, selfn, bufC);
    k_scatter<80><<<cdiv(EE * 20LL, BS), BS, 0, stream>>>(bufA, src, dst, norm, bufC);
    k_mm_vec<80, 160, 1, true, false><<<cdiv((NN / 8) * 160LL, BS), BS, 0, stream>>>(
        bufC, dg3_w, dg3_b, bufB, nullptr, nullptr);

    // ---- dg4 (160->3), MM-first, tanh ----
    k_mm_vec<160, 3, 0, false, true><<<cdiv((NN / 8) * 3LL, BS), BS, 0, stream>>>(
        bufB, dg4_w, nullptr, bufA, selfn, bufC);
    k_scatter3<<<cdiv(EE, BS), BS, 0, stream>>>(bufA, src, dst, norm, bufC);
    k_fin<3, 2><<<cdiv(3LL * NN, BS), BS, 0, stream>>>(bufC, dg4_b, out);
}

// Round 2
// 1268.175 us; speedup vs baseline: 6.2329x; 6.2329x over previous
//
#include <hip/hip_runtime.h>
#include <math.h>

#define BS 256
static constexpr int NN = 100000;   // nodes
static constexpr int EE = 1600000;  // directed edges (excl. self loops)
static constexpr int SCAN_ELEMS = 1024;           // elements per scan block
static constexpr int SCAN_NB = (NN + SCAN_ELEMS - 1) / SCAN_ELEMS;  // 98

static inline int cdiv(long long a, int b) { return (int)((a + b - 1) / b); }

// ---------------- activation ----------------
template <int ACT>
__device__ __forceinline__ float act_f(float v) {
    if (ACT == 1) return fmaxf(v, 0.0f);
    if (ACT == 2) return tanhf(v);
    return v;
}

// ---------------- CSR build ----------------
__global__ void k_zero(int* __restrict__ cnt) {
    int i = blockIdx.x * BS + threadIdx.x;
    if (i < NN) cnt[i] = 0;
}

__global__ void k_count(const int* __restrict__ dst, int* __restrict__ cnt) {
    int e = blockIdx.x * BS + threadIdx.x;
    if (e < EE) atomicAdd(&cnt[dst[e]], 1);
}

__global__ void k_deg(const int* __restrict__ cnt, float* __restrict__ dis,
                      float* __restrict__ selfn) {
    int i = blockIdx.x * BS + threadIdx.x;
    if (i < NN) {
        float d = (float)(cnt[i] + 1);  // + self loop
        dis[i] = rsqrtf(d);
        selfn[i] = 1.0f / d;
    }
}

// block-local exclusive scan: each block handles 1024 elems (4/thread)
__global__ void k_scan1(const int* __restrict__ cnt, int* __restrict__ outp,
                        int* __restrict__ bsums) {
    __shared__ int lds[BS];
    int base = blockIdx.x * SCAN_ELEMS;
    int t = threadIdx.x;
    int v[4];
    int s = 0;
#pragma unroll
    for (int j = 0; j < 4; ++j) {
        int idx = base + t * 4 + j;
        v[j] = (idx < NN) ? cnt[idx] : 0;
        s += v[j];
    }
    lds[t] = s;
    __syncthreads();
    for (int off = 1; off < BS; off <<= 1) {
        int add = (t >= off) ? lds[t - off] : 0;
        __syncthreads();
        lds[t] += add;
        __syncthreads();
    }
    int run = lds[t] - s;  // exclusive prefix for this thread within block
    if (t == BS - 1) bsums[blockIdx.x] = lds[BS - 1];
#pragma unroll
    for (int j = 0; j < 4; ++j) {
        int idx = base + t * 4 + j;
        if (idx < NN) outp[idx] = run;
        run += v[j];
    }
}

__global__ void k_scan2(int* __restrict__ bsums) {
    if (blockIdx.x == 0 && threadIdx.x == 0) {
        int acc = 0;
        for (int i = 0; i < SCAN_NB; ++i) {
            int t = bsums[i];
            bsums[i] = acc;
            acc += t;
        }
    }
}

__global__ void k_scan3(int* __restrict__ rowptr, const int* __restrict__ bsums,
                        int* __restrict__ cursor) {
    int i = blockIdx.x * BS + threadIdx.x;
    if (i < NN) {
        int r = rowptr[i] + bsums[i / SCAN_ELEMS];
        rowptr[i] = r;
        cursor[i] = r;
    }
    if (i == 0) rowptr[NN] = EE;
}

__global__ void k_fill(const int* __restrict__ src, const int* __restrict__ dst,
                       const float* __restrict__ dis, int* __restrict__ cursor,
                       int2* __restrict__ epack) {
    int e = blockIdx.x * BS + threadIdx.x;
    if (e >= EE) return;
    int s = src[e], d = dst[e];
    int pos = atomicAdd(&cursor[d], 1);
    float w = dis[s] * dis[d];
    epack[pos] = make_int2(s, __float_as_int(w));
}

// ---------------- CSR gather aggregation ----------------
// out[n,:] = act( h[n,:]*selfn[n] + sum_{e in CSR[n]} h[src_e,:]*w_e  (+b) )
template <int C, int ACT, bool HASB>
__global__ void k_gather4(const float* __restrict__ h, const int* __restrict__ rowptr,
                          const int2* __restrict__ epack, const float* __restrict__ selfn,
                          const float* __restrict__ b, float* __restrict__ out) {
    static_assert(C % 4 == 0, "C%4");
    constexpr int V = C / 4;
    int t = blockIdx.x * BS + threadIdx.x;
    if (t >= NN * V) return;
    int n = t / V, v = t % V;
    const float4* h4 = (const float4*)h;
    float4 acc = h4[(size_t)n * V + v];
    float sn = selfn[n];
    acc.x *= sn; acc.y *= sn; acc.z *= sn; acc.w *= sn;
    int rs = rowptr[n], re = rowptr[n + 1];
    for (int k = rs; k < re; ++k) {
        int2 p = epack[k];
        float w = __int_as_float(p.y);
        float4 hv = h4[(size_t)p.x * V + v];
        acc.x = fmaf(hv.x, w, acc.x);
        acc.y = fmaf(hv.y, w, acc.y);
        acc.z = fmaf(hv.z, w, acc.z);
        acc.w = fmaf(hv.w, w, acc.w);
    }
    if (HASB) {
        const float4* b4 = (const float4*)b;
        float4 bb = b4[v];
        acc.x += bb.x; acc.y += bb.y; acc.z += bb.z; acc.w += bb.w;
    }
    acc.x = act_f<ACT>(acc.x);
    acc.y = act_f<ACT>(acc.y);
    acc.z = act_f<ACT>(acc.z);
    acc.w = act_f<ACT>(acc.w);
    ((float4*)out)[(size_t)n * V + v] = acc;
}

template <int ACT, bool HASB>
__global__ void k_gather3(const float* __restrict__ h, const int* __restrict__ rowptr,
                          const int2* __restrict__ epack, const float* __restrict__ selfn,
                          const float* __restrict__ b, float* __restrict__ out) {
    int n = blockIdx.x * BS + threadIdx.x;
    if (n >= NN) return;
    float sn = selfn[n];
    const float* hp = h + (size_t)n * 3;
    float a0 = hp[0] * sn, a1 = hp[1] * sn, a2 = hp[2] * sn;
    int rs = rowptr[n], re = rowptr[n + 1];
    for (int k = rs; k < re; ++k) {
        int2 p = epack[k];
        float w = __int_as_float(p.y);
        const float* hq = h + (size_t)p.x * 3;
        a0 = fmaf(hq[0], w, a0);
        a1 = fmaf(hq[1], w, a1);
        a2 = fmaf(hq[2], w, a2);
    }
    if (HASB) { a0 += b[0]; a1 += b[1]; a2 += b[2]; }
    float* op = out + (size_t)n * 3;
    op[0] = act_f<ACT>(a0);
    op[1] = act_f<ACT>(a1);
    op[2] = act_f<ACT>(a2);
}

// ---------------- simple matmul (small CIN): thread per output elem ----------------
template <int CIN, int COUT, int ACT, bool HASB>
__global__ void k_mm_simple(const float* __restrict__ x, const float* __restrict__ w,
                            const float* __restrict__ b, float* __restrict__ out) {
    int i = blockIdx.x * BS + threadIdx.x;
    if (i >= NN * COUT) return;
    int n = i / COUT, c = i % COUT;
    const float* xr = x + (size_t)n * CIN;
    float acc = HASB ? b[c] : 0.0f;
#pragma unroll
    for (int ci = 0; ci < CIN; ++ci) acc = fmaf(xr[ci], w[ci * COUT + c], acc);
    out[i] = act_f<ACT>(acc);
}

// ---------------- vectorized matmul: thread computes TM=8 rows for one col ----------------
template <int CIN, int COUT, int ACT, bool HASB>
__global__ void k_mm_vec(const float* __restrict__ x, const float* __restrict__ w,
                         const float* __restrict__ b, float* __restrict__ out) {
    static_assert(CIN % 4 == 0, "CIN%4");
    constexpr int TM = 8;
    constexpr int CIN4 = CIN / 4;
    constexpr int RG = NN / TM;  // 12500
    int i = blockIdx.x * BS + threadIdx.x;
    if (i >= RG * COUT) return;
    int c = i % COUT;
    int n0 = (i / COUT) * TM;
    float acc[TM];
    float bb = HASB ? b[c] : 0.0f;
#pragma unroll
    for (int r = 0; r < TM; ++r) acc[r] = bb;
    const float4* x4 = (const float4*)x;
    for (int k = 0; k < CIN4; ++k) {
        float w0 = w[(4 * k + 0) * COUT + c];
        float w1 = w[(4 * k + 1) * COUT + c];
        float w2 = w[(4 * k + 2) * COUT + c];
        float w3 = w[(4 * k + 3) * COUT + c];
#pragma unroll
        for (int r = 0; r < TM; ++r) {
            float4 xv = x4[(size_t)(n0 + r) * CIN4 + k];
            acc[r] = fmaf(xv.x, w0, fmaf(xv.y, w1, fmaf(xv.z, w2, fmaf(xv.w, w3, acc[r]))));
        }
    }
#pragma unroll
    for (int r = 0; r < TM; ++r) {
        out[(size_t)(n0 + r) * COUT + c] = act_f<ACT>(acc[r]);
    }
}

extern "C" void kernel_launch(void* const* d_in, const int* in_sizes, int n_in,
                              void* d_out, int out_size, void* d_ws, size_t ws_size,
                              hipStream_t stream) {
    const float* x = (const float*)d_in[0];
    const int* ei = (const int*)d_in[1];
    const int* src = ei;
    const int* dst = ei + EE;
    const float* eg1_w = (const float*)d_in[2];  const float* eg1_b = (const float*)d_in[3];
    const float* eg2_w = (const float*)d_in[4];  const float* eg2_b = (const float*)d_in[5];
    const float* eg3_w = (const float*)d_in[6];  const float* eg3_b = (const float*)d_in[7];
    const float* eg4_w = (const float*)d_in[8];  const float* eg4_b = (const float*)d_in[9];
    const float* el1_w = (const float*)d_in[10]; const float* el1_b = (const float*)d_in[11];
    const float* el2_w = (const float*)d_in[12]; const float* el2_b = (const float*)d_in[13];
    const float* dl1_w = (const float*)d_in[14]; const float* dl1_b = (const float*)d_in[15];
    const float* dl2_w = (const float*)d_in[16]; const float* dl2_b = (const float*)d_in[17];
    const float* dg1_w = (const float*)d_in[18]; const float* dg1_b = (const float*)d_in[19];
    const float* dg2_w = (const float*)d_in[20]; const float* dg2_b = (const float*)d_in[21];
    const float* dg3_w = (const float*)d_in[22]; const float* dg3_b = (const float*)d_in[23];
    const float* dg4_w = (const float*)d_in[24]; const float* dg4_b = (const float*)d_in[25];
    float* out = (float*)d_out;

    // workspace layout
    char* ws = (char*)d_ws;
    size_t off = 0;
    auto alloc = [&](size_t bytes) {
        void* p = ws + off;
        off += (bytes + 15) & ~(size_t)15;  // 16B align
        return p;
    };
    int* cnt    = (int*)alloc(sizeof(int) * NN);
    int* rowptr = (int*)alloc(sizeof(int) * (NN + 1));
    int* cursor = (int*)alloc(sizeof(int) * NN);
    int* bsums  = (int*)alloc(sizeof(int) * SCAN_NB);
    float* dis   = (float*)alloc(sizeof(float) * NN);
    float* selfn = (float*)alloc(sizeof(float) * NN);
    int2* epack  = (int2*)alloc(sizeof(int2) * EE);
    float* bufA  = (float*)alloc(sizeof(float) * 160 * (size_t)NN);
    float* bufB  = (float*)alloc(sizeof(float) * 160 * (size_t)NN);

    // ---- CSR build ----
    k_zero<<<cdiv(NN, BS), BS, 0, stream>>>(cnt);
    k_count<<<cdiv(EE, BS), BS, 0, stream>>>(dst, cnt);
    k_deg<<<cdiv(NN, BS), BS, 0, stream>>>(cnt, dis, selfn);
    k_scan1<<<SCAN_NB, BS, 0, stream>>>(cnt, rowptr, bsums);
    k_scan2<<<1, 64, 0, stream>>>(bsums);
    k_scan3<<<cdiv(NN, BS), BS, 0, stream>>>(rowptr, bsums, cursor);
    k_fill<<<cdiv(EE, BS), BS, 0, stream>>>(src, dst, dis, cursor, epack);

    // ---- eg1 (3->160): AGG-first ----
    k_gather3<0, false><<<cdiv(NN, BS), BS, 0, stream>>>(x, rowptr, epack, selfn, nullptr, bufA);
    k_mm_simple<3, 160, 1, true><<<cdiv(160LL * NN, BS), BS, 0, stream>>>(bufA, eg1_w, eg1_b, bufB);

    // ---- eg2 (160->80): MM-first ----
    k_mm_vec<160, 80, 0, false><<<cdiv((NN / 8) * 80LL, BS), BS, 0, stream>>>(bufB, eg2_w, nullptr, bufA);
    k_gather4<80, 1, true><<<cdiv(NN * 20LL, BS), BS, 0, stream>>>(bufA, rowptr, epack, selfn, eg2_b, bufB);

    // ---- eg3 (80->40): MM-first ----
    k_mm_vec<80, 40, 0, false><<<cdiv((NN / 8) * 40LL, BS), BS, 0, stream>>>(bufB, eg3_w, nullptr, bufA);
    k_gather4<40, 1, true><<<cdiv(NN * 10LL, BS), BS, 0, stream>>>(bufA, rowptr, epack, selfn, eg3_b, bufB);

    // ---- eg4 (40->20): MM-first ----
    k_mm_vec<40, 20, 0, false><<<cdiv((NN / 8) * 20LL, BS), BS, 0, stream>>>(bufB, eg4_w, nullptr, bufA);
    k_gather4<20, 1, true><<<cdiv(NN * 5LL, BS), BS, 0, stream>>>(bufA, rowptr, epack, selfn, eg4_b, bufB);

    // ---- dense latent stack ----
    k_mm_vec<20, 10, 1, true><<<cdiv((NN / 8) * 10LL, BS), BS, 0, stream>>>(bufB, el1_w, el1_b, bufA);
    k_mm_simple<10, 3, 0, true><<<cdiv(3LL * NN, BS), BS, 0, stream>>>(bufA, el2_w, el2_b, bufB);
    k_mm_simple<3, 10, 1, true><<<cdiv(10LL * NN, BS), BS, 0, stream>>>(bufB, dl1_w, dl1_b, bufA);
    k_mm_simple<10, 20, 1, true><<<cdiv(20LL * NN, BS), BS, 0, stream>>>(bufA, dl2_w, dl2_b, bufB);

    // ---- dg1 (20->40): AGG-first ----
    k_gather4<20, 0, false><<<cdiv(NN * 5LL, BS), BS, 0, stream>>>(bufB, rowptr, epack, selfn, nullptr, bufA);
    k_mm_vec<20, 40, 1, true><<<cdiv((NN / 8) * 40LL, BS), BS, 0, stream>>>(bufA, dg1_w, dg1_b, bufB);

    // ---- dg2 (40->80): AGG-first ----
    k_gather4<40, 0, false><<<cdiv(NN * 10LL, BS), BS, 0, stream>>>(bufB, rowptr, epack, selfn, nullptr, bufA);
    k_mm_vec<40, 80, 1, true><<<cdiv((NN / 8) * 80LL, BS), BS, 0, stream>>>(bufA, dg2_w, dg2_b, bufB);

    // ---- dg3 (80->160): AGG-first ----
    k_gather4<80, 0, false><<<cdiv(NN * 20LL, BS), BS, 0, stream>>>(bufB, rowptr, epack, selfn, nullptr, bufA);
    k_mm_vec<80, 160, 1, true><<<cdiv((NN / 8) * 160LL, BS), BS, 0, stream>>>(bufA, dg3_w, dg3_b, bufB);

    // ---- dg4 (160->3): MM-first, tanh ----
    k_mm_vec<160, 3, 0, false><<<cdiv((NN / 8) * 3LL, BS), BS, 0, stream>>>(bufB, dg4_w, nullptr, bufA);
    k_gather3<2, true><<<cdiv(NN, BS), BS, 0, stream>>>(bufA, rowptr, epack, selfn, dg4_b, out);
}

// Round 3
// 954.873 us; speedup vs baseline: 8.2780x; 1.3281x over previous
//
#include <hip/hip_runtime.h>
#include <math.h>

#define BS 256
static constexpr int NN = 100000;   // nodes
static constexpr int EE = 1600000;  // directed edges (excl. self loops)
static constexpr int SCAN_ELEMS = 1024;           // elements per scan block
static constexpr int SCAN_NB = (NN + SCAN_ELEMS - 1) / SCAN_ELEMS;  // 98

static inline int cdiv(long long a, int b) { return (int)((a + b - 1) / b); }

// ---------------- activation ----------------
template <int ACT>
__device__ __forceinline__ float act_f(float v) {
    if (ACT == 1) return fmaxf(v, 0.0f);
    if (ACT == 2) return tanhf(v);
    return v;
}

// ---------------- CSR build ----------------
__global__ void k_zero(int* __restrict__ cnt) {
    int i = blockIdx.x * BS + threadIdx.x;
    if (i < NN) cnt[i] = 0;
}

__global__ void k_count(const int* __restrict__ dst, int* __restrict__ cnt) {
    int e = blockIdx.x * BS + threadIdx.x;
    if (e < EE) atomicAdd(&cnt[dst[e]], 1);
}

__global__ void k_deg(const int* __restrict__ cnt, float* __restrict__ dis,
                      float* __restrict__ selfn) {
    int i = blockIdx.x * BS + threadIdx.x;
    if (i < NN) {
        float d = (float)(cnt[i] + 1);  // + self loop
        dis[i] = rsqrtf(d);
        selfn[i] = 1.0f / d;
    }
}

// block-local exclusive scan: each block handles 1024 elems (4/thread)
__global__ void k_scan1(const int* __restrict__ cnt, int* __restrict__ outp,
                        int* __restrict__ bsums) {
    __shared__ int lds[BS];
    int base = blockIdx.x * SCAN_ELEMS;
    int t = threadIdx.x;
    int v[4];
    int s = 0;
#pragma unroll
    for (int j = 0; j < 4; ++j) {
        int idx = base + t * 4 + j;
        v[j] = (idx < NN) ? cnt[idx] : 0;
        s += v[j];
    }
    lds[t] = s;
    __syncthreads();
    for (int off = 1; off < BS; off <<= 1) {
        int add = (t >= off) ? lds[t - off] : 0;
        __syncthreads();
        lds[t] += add;
        __syncthreads();
    }
    int run = lds[t] - s;  // exclusive prefix for this thread within block
    if (t == BS - 1) bsums[blockIdx.x] = lds[BS - 1];
#pragma unroll
    for (int j = 0; j < 4; ++j) {
        int idx = base + t * 4 + j;
        if (idx < NN) outp[idx] = run;
        run += v[j];
    }
}

__global__ void k_scan2(int* __restrict__ bsums) {
    if (blockIdx.x == 0 && threadIdx.x == 0) {
        int acc = 0;
        for (int i = 0; i < SCAN_NB; ++i) {
            int t = bsums[i];
            bsums[i] = acc;
            acc += t;
        }
    }
}

__global__ void k_scan3(int* __restrict__ rowptr, const int* __restrict__ bsums,
                        int* __restrict__ cursor) {
    int i = blockIdx.x * BS + threadIdx.x;
    if (i < NN) {
        int r = rowptr[i] + bsums[i / SCAN_ELEMS];
        rowptr[i] = r;
        cursor[i] = r;
    }
    if (i == 0) rowptr[NN] = EE;
}

__global__ void k_fill(const int* __restrict__ src, const int* __restrict__ dst,
                       const float* __restrict__ dis, int* __restrict__ cursor,
                       int2* __restrict__ epack) {
    int e = blockIdx.x * BS + threadIdx.x;
    if (e >= EE) return;
    int s = src[e], d = dst[e];
    int pos = atomicAdd(&cursor[d], 1);
    float w = dis[s] * dis[d];
    epack[pos] = make_int2(s, __float_as_int(w));
}

// ---------------- CSR gather aggregation ----------------
template <int C, int ACT, bool HASB>
__global__ void k_gather4(const float* __restrict__ h, const int* __restrict__ rowptr,
                          const int2* __restrict__ epack, const float* __restrict__ selfn,
                          const float* __restrict__ b, float* __restrict__ out) {
    static_assert(C % 4 == 0, "C%4");
    constexpr int V = C / 4;
    int t = blockIdx.x * BS + threadIdx.x;
    if (t >= NN * V) return;
    int n = t / V, v = t % V;
    const float4* h4 = (const float4*)h;
    float4 acc = h4[(size_t)n * V + v];
    float sn = selfn[n];
    acc.x *= sn; acc.y *= sn; acc.z *= sn; acc.w *= sn;
    int rs = rowptr[n], re = rowptr[n + 1];
    for (int k = rs; k < re; ++k) {
        int2 p = epack[k];
        float w = __int_as_float(p.y);
        float4 hv = h4[(size_t)p.x * V + v];
        acc.x = fmaf(hv.x, w, acc.x);
        acc.y = fmaf(hv.y, w, acc.y);
        acc.z = fmaf(hv.z, w, acc.z);
        acc.w = fmaf(hv.w, w, acc.w);
    }
    if (HASB) {
        const float4* b4 = (const float4*)b;
        float4 bb = b4[v];
        acc.x += bb.x; acc.y += bb.y; acc.z += bb.z; acc.w += bb.w;
    }
    acc.x = act_f<ACT>(acc.x);
    acc.y = act_f<ACT>(acc.y);
    acc.z = act_f<ACT>(acc.z);
    acc.w = act_f<ACT>(acc.w);
    ((float4*)out)[(size_t)n * V + v] = acc;
}

template <int ACT, bool HASB>
__global__ void k_gather3(const float* __restrict__ h, const int* __restrict__ rowptr,
                          const int2* __restrict__ epack, const float* __restrict__ selfn,
                          const float* __restrict__ b, float* __restrict__ out) {
    int n = blockIdx.x * BS + threadIdx.x;
    if (n >= NN) return;
    float sn = selfn[n];
    const float* hp = h + (size_t)n * 3;
    float a0 = hp[0] * sn, a1 = hp[1] * sn, a2 = hp[2] * sn;
    int rs = rowptr[n], re = rowptr[n + 1];
    for (int k = rs; k < re; ++k) {
        int2 p = epack[k];
        float w = __int_as_float(p.y);
        const float* hq = h + (size_t)p.x * 3;
        a0 = fmaf(hq[0], w, a0);
        a1 = fmaf(hq[1], w, a1);
        a2 = fmaf(hq[2], w, a2);
    }
    if (HASB) { a0 += b[0]; a1 += b[1]; a2 += b[2]; }
    float* op = out + (size_t)n * 3;
    op[0] = act_f<ACT>(a0);
    op[1] = act_f<ACT>(a1);
    op[2] = act_f<ACT>(a2);
}

// ---------------- LDS-tiled SGEMM ----------------
// 256 threads; block computes BM=TR*TM rows x COUT cols. x-tile staged
// transposed in LDS (read once from global); w-chunk staged in LDS.
template <int CIN, int COUT, int TC, int TN, int TM, int BK, int ACT, bool HASB>
__global__ __launch_bounds__(256) void k_mm_tiled(const float* __restrict__ x,
                                                  const float* __restrict__ w,
                                                  const float* __restrict__ b,
                                                  float* __restrict__ out) {
    constexpr int TR = 256 / TC;
    constexpr int BM = TR * TM;
    constexpr int LDA = BM + 4;   // pad: bank stride 4 per k-row
    constexpr int CHUNKS = CIN / BK;
    constexpr int BK4 = BK / 4;
    constexpr int CIN4 = CIN / 4;
    static_assert(TC * TN == COUT, "cols");
    static_assert(CIN % BK == 0 && BK % 4 == 0, "bk");
    static_assert(TM == 4 || TM == 8, "tm");
    __shared__ float As[BK * LDA];
    __shared__ float Ws[BK * COUT];
    const int tid = threadIdx.x;
    const int tc = tid % TC, tr = tid / TC;
    const int n0 = blockIdx.x * BM;

    float acc[TM][TN];
#pragma unroll
    for (int r = 0; r < TM; ++r)
#pragma unroll
        for (int j = 0; j < TN; ++j) acc[r][j] = HASB ? b[tc * TN + j] : 0.0f;

    const float4* x4 = (const float4*)x;
    const float4* w4 = (const float4*)w;

    for (int ch = 0; ch < CHUNKS; ++ch) {
        const int kb4 = ch * BK4;
        if (ch) __syncthreads();
        // stage A (transposed): As[k][r] = x[n0+r][kb+k]
        for (int i = tid; i < BM * BK4; i += 256) {
            int r = i / BK4, k4 = i % BK4;
            int row = n0 + r;
            float4 v = make_float4(0.f, 0.f, 0.f, 0.f);
            if (row < NN) v = x4[(size_t)row * CIN4 + kb4 + k4];
            int base = (4 * k4) * LDA + r;
            As[base] = v.x;
            As[base + LDA] = v.y;
            As[base + 2 * LDA] = v.z;
            As[base + 3 * LDA] = v.w;
        }
        // stage W (flat copy of BK consecutive rows)
        for (int i = tid; i < BK * COUT / 4; i += 256) {
            ((float4*)Ws)[i] = w4[(size_t)kb4 * COUT + i];
        }
        __syncthreads();
#pragma unroll 4
        for (int k = 0; k < BK; ++k) {
            float a[TM];
            *(float4*)&a[0] = *(const float4*)&As[k * LDA + tr * TM];
            if (TM == 8) *(float4*)&a[4] = *(const float4*)&As[k * LDA + tr * TM + 4];
            float wr[TN];
#pragma unroll
            for (int j = 0; j < TN; ++j) wr[j] = Ws[k * COUT + tc * TN + j];
#pragma unroll
            for (int r = 0; r < TM; ++r)
#pragma unroll
                for (int j = 0; j < TN; ++j) acc[r][j] = fmaf(a[r], wr[j], acc[r][j]);
        }
    }
#pragma unroll
    for (int r = 0; r < TM; ++r) {
        int row = n0 + tr * TM + r;
        if (row < NN) {
            float* op = out + (size_t)row * COUT + tc * TN;
#pragma unroll
            for (int j = 0; j < TN; ++j) op[j] = act_f<ACT>(acc[r][j]);
        }
    }
}

// ---------------- mm_vec4: TM=8 rows x 4 cols per thread (float4 weights) ----------------
template <int CIN, int COUT, int ACT, bool HASB>
__global__ void k_mm_vec4(const float* __restrict__ x, const float* __restrict__ w,
                          const float* __restrict__ b, float* __restrict__ out) {
    static_assert(CIN % 4 == 0 && COUT % 4 == 0, "align");
    constexpr int TM = 8;
    constexpr int CIN4 = CIN / 4;
    constexpr int COUT4 = COUT / 4;
    constexpr int RG = NN / TM;  // 12500
    int i = blockIdx.x * BS + threadIdx.x;
    if (i >= RG * COUT4) return;
    int c4 = i % COUT4;
    int n0 = (i / COUT4) * TM;
    const float4* x4 = (const float4*)x;
    const float4* w4 = (const float4*)w;
    float4 acc[TM];
    float4 bb = HASB ? ((const float4*)b)[c4] : make_float4(0.f, 0.f, 0.f, 0.f);
#pragma unroll
    for (int r = 0; r < TM; ++r) acc[r] = bb;
    for (int k4 = 0; k4 < CIN4; ++k4) {
        float4 wv[4];
#pragma unroll
        for (int j = 0; j < 4; ++j) wv[j] = w4[(size_t)(4 * k4 + j) * COUT4 + c4];
#pragma unroll
        for (int r = 0; r < TM; ++r) {
            float4 xv = x4[(size_t)(n0 + r) * CIN4 + k4];
            acc[r].x = fmaf(xv.x, wv[0].x, fmaf(xv.y, wv[1].x, fmaf(xv.z, wv[2].x, fmaf(xv.w, wv[3].x, acc[r].x))));
            acc[r].y = fmaf(xv.x, wv[0].y, fmaf(xv.y, wv[1].y, fmaf(xv.z, wv[2].y, fmaf(xv.w, wv[3].y, acc[r].y))));
            acc[r].z = fmaf(xv.x, wv[0].z, fmaf(xv.y, wv[1].z, fmaf(xv.z, wv[2].z, fmaf(xv.w, wv[3].z, acc[r].z))));
            acc[r].w = fmaf(xv.x, wv[0].w, fmaf(xv.y, wv[1].w, fmaf(xv.z, wv[2].w, fmaf(xv.w, wv[3].w, acc[r].w))));
        }
    }
#pragma unroll
    for (int r = 0; r < TM; ++r) {
        float4 v = acc[r];
        v.x = act_f<ACT>(v.x); v.y = act_f<ACT>(v.y);
        v.z = act_f<ACT>(v.z); v.w = act_f<ACT>(v.w);
        ((float4*)out)[(size_t)(n0 + r) * COUT4 + c4] = v;
    }
}

// ---------------- small-CIN matmul, float4 output (write-bound layers) ----------------
template <int CIN, int COUT, int ACT>
__global__ void k_mm_rowbcast(const float* __restrict__ x, const float* __restrict__ w,
                              const float* __restrict__ b, float* __restrict__ out) {
    static_assert(COUT % 4 == 0, "c4");
    constexpr int COUT4 = COUT / 4;
    int i = blockIdx.x * BS + threadIdx.x;
    if (i >= NN * COUT4) return;
    int n = i / COUT4, c4 = i % COUT4;
    const float4* w4 = (const float4*)w;
    float4 acc = ((const float4*)b)[c4];
    const float* xr = x + (size_t)n * CIN;
#pragma unroll
    for (int ci = 0; ci < CIN; ++ci) {
        float xv = xr[ci];
        float4 wv = w4[ci * COUT4 + c4];
        acc.x = fmaf(xv, wv.x, acc.x);
        acc.y = fmaf(xv, wv.y, acc.y);
        acc.z = fmaf(xv, wv.z, acc.z);
        acc.w = fmaf(xv, wv.w, acc.w);
    }
    acc.x = act_f<ACT>(acc.x); acc.y = act_f<ACT>(acc.y);
    acc.z = act_f<ACT>(acc.z); acc.w = act_f<ACT>(acc.w);
    ((float4*)out)[(size_t)n * COUT4 + c4] = acc;
}

// ---------------- simple matmul (tiny layers) ----------------
template <int CIN, int COUT, int ACT, bool HASB>
__global__ void k_mm_simple(const float* __restrict__ x, const float* __restrict__ w,
                            const float* __restrict__ b, float* __restrict__ out) {
    int i = blockIdx.x * BS + threadIdx.x;
    if (i >= NN * COUT) return;
    int n = i / COUT, c = i % COUT;
    const float* xr = x + (size_t)n * CIN;
    float acc = HASB ? b[c] : 0.0f;
#pragma unroll
    for (int ci = 0; ci < CIN; ++ci) acc = fmaf(xr[ci], w[ci * COUT + c], acc);
    out[i] = act_f<ACT>(acc);
}

// ---------------- old vec matmul (COUT not %4 or tiny) ----------------
template <int CIN, int COUT, int ACT, bool HASB>
__global__ void k_mm_vec(const float* __restrict__ x, const float* __restrict__ w,
                         const float* __restrict__ b, float* __restrict__ out) {
    static_assert(CIN % 4 == 0, "CIN%4");
    constexpr int TM = 8;
    constexpr int CIN4 = CIN / 4;
    constexpr int RG = NN / TM;  // 12500
    int i = blockIdx.x * BS + threadIdx.x;
    if (i >= RG * COUT) return;
    int c = i % COUT;
    int n0 = (i / COUT) * TM;
    float acc[TM];
    float bb = HASB ? b[c] : 0.0f;
#pragma unroll
    for (int r = 0; r < TM; ++r) acc[r] = bb;
    const float4* x4 = (const float4*)x;
    for (int k = 0; k < CIN4; ++k) {
        float w0 = w[(4 * k + 0) * COUT + c];
        float w1 = w[(4 * k + 1) * COUT + c];
        float w2 = w[(4 * k + 2) * COUT + c];
        float w3 = w[(4 * k + 3) * COUT + c];
#pragma unroll
        for (int r = 0; r < TM; ++r) {
            float4 xv = x4[(size_t)(n0 + r) * CIN4 + k];
            acc[r] = fmaf(xv.x, w0, fmaf(xv.y, w1, fmaf(xv.z, w2, fmaf(xv.w, w3, acc[r]))));
        }
    }
#pragma unroll
    for (int r = 0; r < TM; ++r) {
        out[(size_t)(n0 + r) * COUT + c] = act_f<ACT>(acc[r]);
    }
}

extern "C" void kernel_launch(void* const* d_in, const int* in_sizes, int n_in,
                              void* d_out, int out_size, void* d_ws, size_t ws_size,
                              hipStream_t stream) {
    const float* x = (const float*)d_in[0];
    const int* ei = (const int*)d_in[1];
    const int* src = ei;
    const int* dst = ei + EE;
    const float* eg1_w = (const float*)d_in[2];  const float* eg1_b = (const float*)d_in[3];
    const float* eg2_w = (const float*)d_in[4];  const float* eg2_b = (const float*)d_in[5];
    const float* eg3_w = (const float*)d_in[6];  const float* eg3_b = (const float*)d_in[7];
    const float* eg4_w = (const float*)d_in[8];  const float* eg4_b = (const float*)d_in[9];
    const float* el1_w = (const float*)d_in[10]; const float* el1_b = (const float*)d_in[11];
    const float* el2_w = (const float*)d_in[12]; const float* el2_b = (const float*)d_in[13];
    const float* dl1_w = (const float*)d_in[14]; const float* dl1_b = (const float*)d_in[15];
    const float* dl2_w = (const float*)d_in[16]; const float* dl2_b = (const float*)d_in[17];
    const float* dg1_w = (const float*)d_in[18]; const float* dg1_b = (const float*)d_in[19];
    const float* dg2_w = (const float*)d_in[20]; const float* dg2_b = (const float*)d_in[21];
    const float* dg3_w = (const float*)d_in[22]; const float* dg3_b = (const float*)d_in[23];
    const float* dg4_w = (const float*)d_in[24]; const float* dg4_b = (const float*)d_in[25];
    float* out = (float*)d_out;

    // workspace layout
    char* ws = (char*)d_ws;
    size_t off = 0;
    auto alloc = [&](size_t bytes) {
        void* p = ws + off;
        off += (bytes + 15) & ~(size_t)15;  // 16B align
        return p;
    };
    int* cnt    = (int*)alloc(sizeof(int) * NN);
    int* rowptr = (int*)alloc(sizeof(int) * (NN + 1));
    int* cursor = (int*)alloc(sizeof(int) * NN);
    int* bsums  = (int*)alloc(sizeof(int) * SCAN_NB);
    float* dis   = (float*)alloc(sizeof(float) * NN);
    float* selfn = (float*)alloc(sizeof(float) * NN);
    int2* epack  = (int2*)alloc(sizeof(int2) * EE);
    float* bufA  = (float*)alloc(sizeof(float) * 160 * (size_t)NN);
    float* bufB  = (float*)alloc(sizeof(float) * 160 * (size_t)NN);

    // ---- CSR build ----
    k_zero<<<cdiv(NN, BS), BS, 0, stream>>>(cnt);
    k_count<<<cdiv(EE, BS), BS, 0, stream>>>(dst, cnt);
    k_deg<<<cdiv(NN, BS), BS, 0, stream>>>(cnt, dis, selfn);
    k_scan1<<<SCAN_NB, BS, 0, stream>>>(cnt, rowptr, bsums);
    k_scan2<<<1, 64, 0, stream>>>(bsums);
    k_scan3<<<cdiv(NN, BS), BS, 0, stream>>>(rowptr, bsums, cursor);
    k_fill<<<cdiv(EE, BS), BS, 0, stream>>>(src, dst, dis, cursor, epack);

    // ---- eg1 (3->160): AGG-first ----
    k_gather3<0, false><<<cdiv(NN, BS), BS, 0, stream>>>(x, rowptr, epack, selfn, nullptr, bufA);
    k_mm_rowbcast<3, 160, 1><<<cdiv(NN * 40LL, BS), BS, 0, stream>>>(bufA, eg1_w, eg1_b, bufB);

    // ---- eg2 (160->80): MM-first, tiled (BM=128, BK=32, 8x5/thread) ----
    k_mm_tiled<160, 80, 16, 5, 8, 32, 0, false><<<cdiv(NN, 128), 256, 0, stream>>>(
        bufB, eg2_w, nullptr, bufA);
    k_gather4<80, 1, true><<<cdiv(NN * 20LL, BS), BS, 0, stream>>>(bufA, rowptr, epack, selfn, eg2_b, bufB);

    // ---- eg3 (80->40): MM-first, tiled (BM=128, BK=40, 4x5/thread) ----
    k_mm_tiled<80, 40, 8, 5, 4, 40, 0, false><<<cdiv(NN, 128), 256, 0, stream>>>(
        bufB, eg3_w, nullptr, bufA);
    k_gather4<40, 1, true><<<cdiv(NN * 10LL, BS), BS, 0, stream>>>(bufA, rowptr, epack, selfn, eg3_b, bufB);

    // ---- eg4 (40->20): MM-first ----
    k_mm_vec4<40, 20, 0, false><<<cdiv((NN / 8) * 5LL, BS), BS, 0, stream>>>(bufB, eg4_w, nullptr, bufA);
    k_gather4<20, 1, true><<<cdiv(NN * 5LL, BS), BS, 0, stream>>>(bufA, rowptr, epack, selfn, eg4_b, bufB);

    // ---- dense latent stack ----
    k_mm_vec<20, 10, 1, true><<<cdiv((NN / 8) * 10LL, BS), BS, 0, stream>>>(bufB, el1_w, el1_b, bufA);
    k_mm_simple<10, 3, 0, true><<<cdiv(3LL * NN, BS), BS, 0, stream>>>(bufA, el2_w, el2_b, bufB);
    k_mm_simple<3, 10, 1, true><<<cdiv(10LL * NN, BS), BS, 0, stream>>>(bufB, dl1_w, dl1_b, bufA);
    k_mm_simple<10, 20, 1, true><<<cdiv(20LL * NN, BS), BS, 0, stream>>>(bufA, dl2_w, dl2_b, bufB);

    // ---- dg1 (20->40): AGG-first ----
    k_gather4<20, 0, false><<<cdiv(NN * 5LL, BS), BS, 0, stream>>>(bufB, rowptr, epack, selfn, nullptr, bufA);
    k_mm_vec4<20, 40, 1, true><<<cdiv((NN / 8) * 10LL, BS), BS, 0, stream>>>(bufA, dg1_w, dg1_b, bufB);

    // ---- dg2 (40->80): AGG-first, tiled (BM=128, BK=40 full-K, 8x5/thread) ----
    k_gather4<40, 0, false><<<cdiv(NN * 10LL, BS), BS, 0, stream>>>(bufB, rowptr, epack, selfn, nullptr, bufA);
    k_mm_tiled<40, 80, 16, 5, 8, 40, 1, true><<<cdiv(NN, 128), 256, 0, stream>>>(
        bufA, dg2_w, dg2_b, bufB);

    // ---- dg3 (80->160): AGG-first, tiled (BM=64, BK=40, 8x5/thread) ----
    k_gather4<80, 0, false><<<cdiv(NN * 20LL, BS), BS, 0, stream>>>(bufB, rowptr, epack, selfn, nullptr, bufA);
    k_mm_tiled<80, 160, 32, 5, 8, 40, 1, true><<<cdiv(NN, 64), 256, 0, stream>>>(
        bufA, dg3_w, dg3_b, bufB);

    // ---- dg4 (160->3): MM-first, tanh ----
    k_mm_vec<160, 3, 0, false><<<cdiv((NN / 8) * 3LL, BS), BS, 0, stream>>>(bufB, dg4_w, nullptr, bufA);
    k_gather3<2, true><<<cdiv(NN, BS), BS, 0, stream>>>(bufA, rowptr, epack, selfn, dg4_b, out);
}

// Round 4
// 859.056 us; speedup vs baseline: 9.2013x; 1.1115x over previous
//
#include <hip/hip_runtime.h>
#include <hip/hip_fp16.h>
#include <math.h>

#define BS 256
static constexpr int NN = 100000;   // nodes
static constexpr int EE = 1600000;  // directed edges (excl. self loops)
static constexpr int SCAN_ELEMS = 1024;           // elements per scan block
static constexpr int SCAN_NB = (NN + SCAN_ELEMS - 1) / SCAN_ELEMS;  // 98

static inline int cdiv(long long a, int b) { return (int)((a + b - 1) / b); }

// ---------------- helpers ----------------
template <int ACT>
__device__ __forceinline__ float act_f(float v) {
    if (ACT == 1) return fmaxf(v, 0.0f);
    if (ACT == 2) return tanhf(v);
    return v;
}

__device__ __forceinline__ unsigned short h16(float v) {
    return __half_as_ushort(__float2half(v));
}
__device__ __forceinline__ unsigned pack2h(float a, float b) {
    return (unsigned)h16(a) | ((unsigned)h16(b) << 16);
}
__device__ __forceinline__ float4 cvt4h(uint2 r) {
    float2 fa = __half22float2(*(const __half2*)&r.x);
    float2 fb = __half22float2(*(const __half2*)&r.y);
    return make_float4(fa.x, fa.y, fb.x, fb.y);
}

// OUTM: 0 = plain fp32, 1 = fp32 * dis[n], 2 = fp16 * dis[n] (ushort* buffer)
template <int OUTM>
__device__ __forceinline__ void store1(float* out, size_t idx, float v, float dn) {
    if (OUTM == 0) out[idx] = v;
    else if (OUTM == 1) out[idx] = v * dn;
    else ((unsigned short*)out)[idx] = h16(v * dn);
}

// ---------------- CSR build ----------------
__global__ void k_zero(int* __restrict__ cnt) {
    int i = blockIdx.x * BS + threadIdx.x;
    if (i < NN) cnt[i] = 0;
}

__global__ void k_count(const int* __restrict__ dst, int* __restrict__ cnt) {
    int e = blockIdx.x * BS + threadIdx.x;
    if (e < EE) atomicAdd(&cnt[dst[e]], 1);
}

__global__ void k_deg(const int* __restrict__ cnt, float* __restrict__ dis) {
    int i = blockIdx.x * BS + threadIdx.x;
    if (i < NN) dis[i] = rsqrtf((float)(cnt[i] + 1));  // + self loop
}

__global__ void k_scan1(const int* __restrict__ cnt, int* __restrict__ outp,
                        int* __restrict__ bsums) {
    __shared__ int lds[BS];
    int base = blockIdx.x * SCAN_ELEMS;
    int t = threadIdx.x;
    int v[4];
    int s = 0;
#pragma unroll
    for (int j = 0; j < 4; ++j) {
        int idx = base + t * 4 + j;
        v[j] = (idx < NN) ? cnt[idx] : 0;
        s += v[j];
    }
    lds[t] = s;
    __syncthreads();
    for (int off = 1; off < BS; off <<= 1) {
        int add = (t >= off) ? lds[t - off] : 0;
        __syncthreads();
        lds[t] += add;
        __syncthreads();
    }
    int run = lds[t] - s;
    if (t == BS - 1) bsums[blockIdx.x] = lds[BS - 1];
#pragma unroll
    for (int j = 0; j < 4; ++j) {
        int idx = base + t * 4 + j;
        if (idx < NN) outp[idx] = run;
        run += v[j];
    }
}

__global__ void k_scan2(int* __restrict__ bsums) {
    if (blockIdx.x == 0 && threadIdx.x == 0) {
        int acc = 0;
        for (int i = 0; i < SCAN_NB; ++i) {
            int t = bsums[i];
            bsums[i] = acc;
            acc += t;
        }
    }
}

__global__ void k_scan3(int* __restrict__ rowptr, const int* __restrict__ bsums,
                        int* __restrict__ cursor) {
    int i = blockIdx.x * BS + threadIdx.x;
    if (i < NN) {
        int r = rowptr[i] + bsums[i / SCAN_ELEMS];
        rowptr[i] = r;
        cursor[i] = r;
    }
    if (i == 0) rowptr[NN] = EE;
}

// fill: only src index per edge (norm folded into node features)
__global__ void k_fill(const int* __restrict__ src, const int* __restrict__ dst,
                       int* __restrict__ cursor, int* __restrict__ eidx) {
    int e = blockIdx.x * BS + threadIdx.x;
    if (e >= EE) return;
    int pos = atomicAdd(&cursor[dst[e]], 1);
    eidx[pos] = src[e];
}

// ---------------- gathers ----------------
// fp16 input g (= dis*h, fp16): out[n,:] = act( dis[n]*(g[n,:]+sum g[src,:]) + b )
template <int C, int ACT, bool HASB>
__global__ void k_gatherh(const unsigned short* __restrict__ g, const int* __restrict__ rowptr,
                          const int* __restrict__ eidx, const float* __restrict__ dis,
                          const float* __restrict__ b, float* __restrict__ out) {
    static_assert(C % 4 == 0, "C%4");
    constexpr int V = C / 4;
    int t = blockIdx.x * BS + threadIdx.x;
    if (t >= NN * V) return;
    int n = t / V, v = t % V;
    const uint2* g2 = (const uint2*)g;
    float4 acc = cvt4h(g2[(size_t)n * V + v]);  // self term
    int rs = rowptr[n], re = rowptr[n + 1];
    for (int k = rs; k < re; ++k) {
        int s = eidx[k];
        float4 hv = cvt4h(g2[(size_t)s * V + v]);
        acc.x += hv.x; acc.y += hv.y; acc.z += hv.z; acc.w += hv.w;
    }
    float dn = dis[n];
    acc.x *= dn; acc.y *= dn; acc.z *= dn; acc.w *= dn;
    if (HASB) {
        float4 bb = ((const float4*)b)[v];
        acc.x += bb.x; acc.y += bb.y; acc.z += bb.z; acc.w += bb.w;
    }
    acc.x = act_f<ACT>(acc.x);
    acc.y = act_f<ACT>(acc.y);
    acc.z = act_f<ACT>(acc.z);
    acc.w = act_f<ACT>(acc.w);
    ((float4*)out)[(size_t)n * V + v] = acc;
}

// fp32 3-channel gather (input g = dis*h fp32): out = act(dis[n]*(g[n]+sum g[src]) + b)
template <int ACT, bool HASB>
__global__ void k_gather3d(const float* __restrict__ g, const int* __restrict__ rowptr,
                           const int* __restrict__ eidx, const float* __restrict__ dis,
                           const float* __restrict__ b, float* __restrict__ out) {
    int n = blockIdx.x * BS + threadIdx.x;
    if (n >= NN) return;
    const float* gp = g + (size_t)n * 3;
    float a0 = gp[0], a1 = gp[1], a2 = gp[2];
    int rs = rowptr[n], re = rowptr[n + 1];
    for (int k = rs; k < re; ++k) {
        const float* gq = g + (size_t)eidx[k] * 3;
        a0 += gq[0]; a1 += gq[1]; a2 += gq[2];
    }
    float dn = dis[n];
    a0 *= dn; a1 *= dn; a2 *= dn;
    if (HASB) { a0 += b[0]; a1 += b[1]; a2 += b[2]; }
    float* op = out + (size_t)n * 3;
    op[0] = act_f<ACT>(a0);
    op[1] = act_f<ACT>(a1);
    op[2] = act_f<ACT>(a2);
}

// prescale: g = x * dis[n] (3ch fp32)
__global__ void k_scale3(const float* __restrict__ x, const float* __restrict__ dis,
                         float* __restrict__ g) {
    int i = blockIdx.x * BS + threadIdx.x;
    if (i < NN * 3) g[i] = x[i] * dis[i / 3];
}

// ---------------- LDS-tiled SGEMM ----------------
template <int CIN, int COUT, int TC, int TN, int TM, int BK, int ACT, bool HASB, int OUTM>
__global__ __launch_bounds__(256) void k_mm_tiled(const float* __restrict__ x,
                                                  const float* __restrict__ w,
                                                  const float* __restrict__ b,
                                                  float* __restrict__ out,
                                                  const float* __restrict__ dis) {
    constexpr int TR = 256 / TC;
    constexpr int BM = TR * TM;
    constexpr int LDA = BM + 4;
    constexpr int CHUNKS = CIN / BK;
    constexpr int BK4 = BK / 4;
    constexpr int CIN4 = CIN / 4;
    static_assert(TC * TN == COUT, "cols");
    static_assert(CIN % BK == 0 && BK % 4 == 0, "bk");
    static_assert(TM == 4 || TM == 8, "tm");
    __shared__ float As[BK * LDA];
    __shared__ float Ws[BK * COUT];
    const int tid = threadIdx.x;
    const int tc = tid % TC, tr = tid / TC;
    const int n0 = blockIdx.x * BM;

    float acc[TM][TN];
#pragma unroll
    for (int r = 0; r < TM; ++r)
#pragma unroll
        for (int j = 0; j < TN; ++j) acc[r][j] = HASB ? b[tc * TN + j] : 0.0f;

    const float4* x4 = (const float4*)x;
    const float4* w4 = (const float4*)w;

    for (int ch = 0; ch < CHUNKS; ++ch) {
        const int kb4 = ch * BK4;
        if (ch) __syncthreads();
        for (int i = tid; i < BM * BK4; i += 256) {
            int r = i / BK4, k4 = i % BK4;
            int row = n0 + r;
            float4 v = make_float4(0.f, 0.f, 0.f, 0.f);
            if (row < NN) v = x4[(size_t)row * CIN4 + kb4 + k4];
            int base = (4 * k4) * LDA + r;
            As[base] = v.x;
            As[base + LDA] = v.y;
            As[base + 2 * LDA] = v.z;
            As[base + 3 * LDA] = v.w;
        }
        for (int i = tid; i < BK * COUT / 4; i += 256) {
            ((float4*)Ws)[i] = w4[(size_t)kb4 * COUT + i];
        }
        __syncthreads();
#pragma unroll 4
        for (int k = 0; k < BK; ++k) {
            float a[TM];
            *(float4*)&a[0] = *(const float4*)&As[k * LDA + tr * TM];
            if (TM == 8) *(float4*)&a[4] = *(const float4*)&As[k * LDA + tr * TM + 4];
            float wr[TN];
#pragma unroll
            for (int j = 0; j < TN; ++j) wr[j] = Ws[k * COUT + tc * TN + j];
#pragma unroll
            for (int r = 0; r < TM; ++r)
#pragma unroll
                for (int j = 0; j < TN; ++j) acc[r][j] = fmaf(a[r], wr[j], acc[r][j]);
        }
    }
#pragma unroll
    for (int r = 0; r < TM; ++r) {
        int row = n0 + tr * TM + r;
        if (row < NN) {
            float dn = (OUTM != 0) ? dis[row] : 0.0f;
            size_t base = (size_t)row * COUT + tc * TN;
#pragma unroll
            for (int j = 0; j < TN; ++j) store1<OUTM>(out, base + j, act_f<ACT>(acc[r][j]), dn);
        }
    }
}

// ---------------- mm_vec4: TM=8 rows x 4 cols per thread ----------------
template <int CIN, int COUT, int ACT, bool HASB, int OUTM>
__global__ void k_mm_vec4(const float* __restrict__ x, const float* __restrict__ w,
                          const float* __restrict__ b, float* __restrict__ out,
                          const float* __restrict__ dis) {
    static_assert(CIN % 4 == 0 && COUT % 4 == 0, "align");
    constexpr int TM = 8;
    constexpr int CIN4 = CIN / 4;
    constexpr int COUT4 = COUT / 4;
    constexpr int RG = NN / TM;
    int i = blockIdx.x * BS + threadIdx.x;
    if (i >= RG * COUT4) return;
    int c4 = i % COUT4;
    int n0 = (i / COUT4) * TM;
    const float4* x4 = (const float4*)x;
    const float4* w4 = (const float4*)w;
    float4 acc[TM];
    float4 bb = HASB ? ((const float4*)b)[c4] : make_float4(0.f, 0.f, 0.f, 0.f);
#pragma unroll
    for (int r = 0; r < TM; ++r) acc[r] = bb;
    for (int k4 = 0; k4 < CIN4; ++k4) {
        float4 wv[4];
#pragma unroll
        for (int j = 0; j < 4; ++j) wv[j] = w4[(size_t)(4 * k4 + j) * COUT4 + c4];
#pragma unroll
        for (int r = 0; r < TM; ++r) {
            float4 xv = x4[(size_t)(n0 + r) * CIN4 + k4];
            acc[r].x = fmaf(xv.x, wv[0].x, fmaf(xv.y, wv[1].x, fmaf(xv.z, wv[2].x, fmaf(xv.w, wv[3].x, acc[r].x))));
            acc[r].y = fmaf(xv.x, wv[0].y, fmaf(xv.y, wv[1].y, fmaf(xv.z, wv[2].y, fmaf(xv.w, wv[3].y, acc[r].y))));
            acc[r].z = fmaf(xv.x, wv[0].z, fmaf(xv.y, wv[1].z, fmaf(xv.z, wv[2].z, fmaf(xv.w, wv[3].z, acc[r].z))));
            acc[r].w = fmaf(xv.x, wv[0].w, fmaf(xv.y, wv[1].w, fmaf(xv.z, wv[2].w, fmaf(xv.w, wv[3].w, acc[r].w))));
        }
    }
#pragma unroll
    for (int r = 0; r < TM; ++r) {
        float vx = act_f<ACT>(acc[r].x), vy = act_f<ACT>(acc[r].y);
        float vz = act_f<ACT>(acc[r].z), vw = act_f<ACT>(acc[r].w);
        size_t gi = (size_t)(n0 + r) * COUT4 + c4;
        if (OUTM == 2) {
            float dn = dis[n0 + r];
            uint2 u;
            u.x = pack2h(vx * dn, vy * dn);
            u.y = pack2h(vz * dn, vw * dn);
            ((uint2*)out)[gi] = u;
        } else if (OUTM == 1) {
            float dn = dis[n0 + r];
            ((float4*)out)[gi] = make_float4(vx * dn, vy * dn, vz * dn, vw * dn);
        } else {
            ((float4*)out)[gi] = make_float4(vx, vy, vz, vw);
        }
    }
}

// ---------------- small-CIN matmul, float4 output ----------------
template <int CIN, int COUT, int ACT>
__global__ void k_mm_rowbcast(const float* __restrict__ x, const float* __restrict__ w,
                              const float* __restrict__ b, float* __restrict__ out) {
    static_assert(COUT % 4 == 0, "c4");
    constexpr int COUT4 = COUT / 4;
    int i = blockIdx.x * BS + threadIdx.x;
    if (i >= NN * COUT4) return;
    int n = i / COUT4, c4 = i % COUT4;
    const float4* w4 = (const float4*)w;
    float4 acc = ((const float4*)b)[c4];
    const float* xr = x + (size_t)n * CIN;
#pragma unroll
    for (int ci = 0; ci < CIN; ++ci) {
        float xv = xr[ci];
        float4 wv = w4[ci * COUT4 + c4];
        acc.x = fmaf(xv, wv.x, acc.x);
        acc.y = fmaf(xv, wv.y, acc.y);
        acc.z = fmaf(xv, wv.z, acc.z);
        acc.w = fmaf(xv, wv.w, acc.w);
    }
    acc.x = act_f<ACT>(acc.x); acc.y = act_f<ACT>(acc.y);
    acc.z = act_f<ACT>(acc.z); acc.w = act_f<ACT>(acc.w);
    ((float4*)out)[(size_t)n * COUT4 + c4] = acc;
}

// ---------------- simple matmul (tiny layers) ----------------
template <int CIN, int COUT, int ACT, bool HASB, int OUTM>
__global__ void k_mm_simple(const float* __restrict__ x, const float* __restrict__ w,
                            const float* __restrict__ b, float* __restrict__ out,
                            const float* __restrict__ dis) {
    int i = blockIdx.x * BS + threadIdx.x;
    if (i >= NN * COUT) return;
    int n = i / COUT, c = i % COUT;
    const float* xr = x + (size_t)n * CIN;
    float acc = HASB ? b[c] : 0.0f;
#pragma unroll
    for (int ci = 0; ci < CIN; ++ci) acc = fmaf(xr[ci], w[ci * COUT + c], acc);
    float dn = (OUTM != 0) ? dis[n] : 0.0f;
    store1<OUTM>(out, (size_t)i, act_f<ACT>(acc), dn);
}

// ---------------- vec matmul (odd COUT) ----------------
template <int CIN, int COUT, int ACT, bool HASB, int OUTM>
__global__ void k_mm_vec(const float* __restrict__ x, const float* __restrict__ w,
                         const float* __restrict__ b, float* __restrict__ out,
                         const float* __restrict__ dis) {
    static_assert(CIN % 4 == 0, "CIN%4");
    constexpr int TM = 8;
    constexpr int CIN4 = CIN / 4;
    constexpr int RG = NN / TM;
    int i = blockIdx.x * BS + threadIdx.x;
    if (i >= RG * COUT) return;
    int c = i % COUT;
    int n0 = (i / COUT) * TM;
    float acc[TM];
    float bb = HASB ? b[c] : 0.0f;
#pragma unroll
    for (int r = 0; r < TM; ++r) acc[r] = bb;
    const float4* x4 = (const float4*)x;
    for (int k = 0; k < CIN4; ++k) {
        float w0 = w[(4 * k + 0) * COUT + c];
        float w1 = w[(4 * k + 1) * COUT + c];
        float w2 = w[(4 * k + 2) * COUT + c];
        float w3 = w[(4 * k + 3) * COUT + c];
#pragma unroll
        for (int r = 0; r < TM; ++r) {
            float4 xv = x4[(size_t)(n0 + r) * CIN4 + k];
            acc[r] = fmaf(xv.x, w0, fmaf(xv.y, w1, fmaf(xv.z, w2, fmaf(xv.w, w3, acc[r]))));
        }
    }
#pragma unroll
    for (int r = 0; r < TM; ++r) {
        int row = n0 + r;
        float dn = (OUTM != 0) ? dis[row] : 0.0f;
        store1<OUTM>(out, (size_t)row * COUT + c, act_f<ACT>(acc[r]), dn);
    }
}

extern "C" void kernel_launch(void* const* d_in, const int* in_sizes, int n_in,
                              void* d_out, int out_size, void* d_ws, size_t ws_size,
                              hipStream_t stream) {
    const float* x = (const float*)d_in[0];
    const int* ei = (const int*)d_in[1];
    const int* src = ei;
    const int* dst = ei + EE;
    const float* eg1_w = (const float*)d_in[2];  const float* eg1_b = (const float*)d_in[3];
    const float* eg2_w = (const float*)d_in[4];  const float* eg2_b = (const float*)d_in[5];
    const float* eg3_w = (const float*)d_in[6];  const float* eg3_b = (const float*)d_in[7];
    const float* eg4_w = (const float*)d_in[8];  const float* eg4_b = (const float*)d_in[9];
    const float* el1_w = (const float*)d_in[10]; const float* el1_b = (const float*)d_in[11];
    const float* el2_w = (const float*)d_in[12]; const float* el2_b = (const float*)d_in[13];
    const float* dl1_w = (const float*)d_in[14]; const float* dl1_b = (const float*)d_in[15];
    const float* dl2_w = (const float*)d_in[16]; const float* dl2_b = (const float*)d_in[17];
    const float* dg1_w = (const float*)d_in[18]; const float* dg1_b = (const float*)d_in[19];
    const float* dg2_w = (const float*)d_in[20]; const float* dg2_b = (const float*)d_in[21];
    const float* dg3_w = (const float*)d_in[22]; const float* dg3_b = (const float*)d_in[23];
    const float* dg4_w = (const float*)d_in[24]; const float* dg4_b = (const float*)d_in[25];
    float* out = (float*)d_out;

    char* ws = (char*)d_ws;
    size_t off = 0;
    auto alloc = [&](size_t bytes) {
        void* p = ws + off;
        off += (bytes + 15) & ~(size_t)15;
        return p;
    };
    int* cnt    = (int*)alloc(sizeof(int) * NN);
    int* rowptr = (int*)alloc(sizeof(int) * (NN + 1));
    int* cursor = (int*)alloc(sizeof(int) * NN);
    int* bsums  = (int*)alloc(sizeof(int) * SCAN_NB);
    float* dis  = (float*)alloc(sizeof(float) * NN);
    int* eidx   = (int*)alloc(sizeof(int) * EE);
    unsigned short* G = (unsigned short*)alloc(sizeof(unsigned short) * 80 * (size_t)NN);
    float* bufA = (float*)alloc(sizeof(float) * 160 * (size_t)NN);
    float* bufB = (float*)alloc(sizeof(float) * 160 * (size_t)NN);

    // ---- CSR build ----
    k_zero<<<cdiv(NN, BS), BS, 0, stream>>>(cnt);
    k_count<<<cdiv(EE, BS), BS, 0, stream>>>(dst, cnt);
    k_deg<<<cdiv(NN, BS), BS, 0, stream>>>(cnt, dis);
    k_scan1<<<SCAN_NB, BS, 0, stream>>>(cnt, rowptr, bsums);
    k_scan2<<<1, 64, 0, stream>>>(bsums);
    k_scan3<<<cdiv(NN, BS), BS, 0, stream>>>(rowptr, bsums, cursor);
    k_fill<<<cdiv(EE, BS), BS, 0, stream>>>(src, dst, cursor, eidx);

    // ---- eg1 (3->160): AGG-first ----
    k_scale3<<<cdiv(3LL * NN, BS), BS, 0, stream>>>(x, dis, bufB);
    k_gather3d<0, false><<<cdiv(NN, BS), BS, 0, stream>>>(bufB, rowptr, eidx, dis, nullptr, bufA);
    k_mm_rowbcast<3, 160, 1><<<cdiv(NN * 40LL, BS), BS, 0, stream>>>(bufA, eg1_w, eg1_b, bufB);

    // ---- eg2 (160->80): MM-first, fp16 g ----
    k_mm_tiled<160, 80, 16, 5, 8, 32, 0, false, 2><<<cdiv(NN, 128), 256, 0, stream>>>(
        bufB, eg2_w, nullptr, (float*)G, dis);
    k_gatherh<80, 1, true><<<cdiv(NN * 20LL, BS), BS, 0, stream>>>(G, rowptr, eidx, dis, eg2_b, bufA);

    // ---- eg3 (80->40): MM-first, fp16 g ----
    k_mm_tiled<80, 40, 8, 5, 4, 40, 0, false, 2><<<cdiv(NN, 128), 256, 0, stream>>>(
        bufA, eg3_w, nullptr, (float*)G, dis);
    k_gatherh<40, 1, true><<<cdiv(NN * 10LL, BS), BS, 0, stream>>>(G, rowptr, eidx, dis, eg3_b, bufB);

    // ---- eg4 (40->20): MM-first, fp16 g ----
    k_mm_vec4<40, 20, 0, false, 2><<<cdiv((NN / 8) * 5LL, BS), BS, 0, stream>>>(
        bufB, eg4_w, nullptr, (float*)G, dis);
    k_gatherh<20, 1, true><<<cdiv(NN * 5LL, BS), BS, 0, stream>>>(G, rowptr, eidx, dis, eg4_b, bufA);

    // ---- dense latent stack ----
    k_mm_vec<20, 10, 1, true, 0><<<cdiv((NN / 8) * 10LL, BS), BS, 0, stream>>>(bufA, el1_w, el1_b, bufB, nullptr);
    k_mm_simple<10, 3, 0, true, 0><<<cdiv(3LL * NN, BS), BS, 0, stream>>>(bufB, el2_w, el2_b, bufA, nullptr);
    k_mm_simple<3, 10, 1, true, 0><<<cdiv(10LL * NN, BS), BS, 0, stream>>>(bufA, dl1_w, dl1_b, bufB, nullptr);
    // dl2 (10->20): relu output scaled by dis -> fp16 g for dg1's gather
    k_mm_simple<10, 20, 1, true, 2><<<cdiv(20LL * NN, BS), BS, 0, stream>>>(bufB, dl2_w, dl2_b, (float*)G, dis);

    // ---- dg1 (20->40): AGG-first ----
    k_gatherh<20, 0, false><<<cdiv(NN * 5LL, BS), BS, 0, stream>>>(G, rowptr, eidx, dis, nullptr, bufA);
    k_mm_vec4<20, 40, 1, true, 2><<<cdiv((NN / 8) * 10LL, BS), BS, 0, stream>>>(
        bufA, dg1_w, dg1_b, (float*)G, dis);

    // ---- dg2 (40->80): AGG-first ----
    k_gatherh<40, 0, false><<<cdiv(NN * 10LL, BS), BS, 0, stream>>>(G, rowptr, eidx, dis, nullptr, bufB);
    k_mm_tiled<40, 80, 16, 5, 8, 40, 1, true, 2><<<cdiv(NN, 128), 256, 0, stream>>>(
        bufB, dg2_w, dg2_b, (float*)G, dis);

    // ---- dg3 (80->160): AGG-first ----
    k_gatherh<80, 0, false><<<cdiv(NN * 20LL, BS), BS, 0, stream>>>(G, rowptr, eidx, dis, nullptr, bufA);
    k_mm_tiled<80, 160, 32, 5, 8, 40, 1, true, 0><<<cdiv(NN, 64), 256, 0, stream>>>(
        bufA, dg3_w, dg3_b, bufB, nullptr);

    // ---- dg4 (160->3): MM-first, tanh; mm writes dis-scaled fp32 g ----
    k_mm_vec<160, 3, 0, false, 1><<<cdiv((NN / 8) * 3LL, BS), BS, 0, stream>>>(bufB, dg4_w, nullptr, bufA, dis);
    k_gather3d<2, true><<<cdiv(NN, BS), BS, 0, stream>>>(bufA, rowptr, eidx, dis, dg4_b, out);
}